// Round 3
// baseline (124.547 us; speedup 1.0000x reference)
//
#include <hip/hip_runtime.h>
#include <hip/hip_bf16.h>
#include <math.h>

#define B 4
#define N 2048
#define FIN 256
#define H 4
#define FO 64
#define M (B*N)        // 8192 rows
#define HF (H*FO)      // 256 cols

typedef __attribute__((ext_vector_type(8))) short short8;    // 8x16b (4 VGPRs)
typedef __attribute__((ext_vector_type(8))) _Float16 half8;  // MFMA f16 A/B
typedef __attribute__((ext_vector_type(2))) _Float16 half2v; // v_pk_* pair
typedef __attribute__((ext_vector_type(4))) float float4v;   // MFMA C/D
typedef __attribute__((ext_vector_type(4))) int int4v;

#if __has_builtin(__builtin_amdgcn_exp2f)
#define EXP2(x) __builtin_amdgcn_exp2f(x)
#else
#define EXP2(x) exp2f(x)
#endif

// split x into hi (truncated bf16) + lo (truncated bf16 of remainder), packed pairs
static __device__ __forceinline__ void split_pair(float x0, float x1,
                                                  unsigned int& hi, unsigned int& lo) {
  unsigned int u0 = __builtin_bit_cast(unsigned int, x0);
  unsigned int u1 = __builtin_bit_cast(unsigned int, x1);
  hi = (u0 >> 16) | (u1 & 0xffff0000u);
  float h0 = __builtin_bit_cast(float, u0 & 0xffff0000u);
  float h1 = __builtin_bit_cast(float, u1 & 0xffff0000u);
  unsigned int l0 = __builtin_bit_cast(unsigned int, x0 - h0);
  unsigned int l1 = __builtin_bit_cast(unsigned int, x1 - h1);
  lo = (l0 >> 16) | (l1 & 0xffff0000u);
}

// monotone float<->uint encoding for atomicMax
static __device__ __forceinline__ unsigned int fenc(float f) {
  unsigned int b = __builtin_bit_cast(unsigned int, f);
  return (b & 0x80000000u) ? ~b : (b | 0x80000000u);
}
static __device__ __forceinline__ float fdec(unsigned int e) {
  unsigned int b = (e & 0x80000000u) ? (e & 0x7fffffffu) : ~e;
  return __builtin_bit_cast(float, b);
}

// two f32 -> packed f16 pair (v_cvt_pkrtz_f16_f32, 1 op)
static __device__ __forceinline__ unsigned int f16pk(float a, float b) {
  auto h = __builtin_amdgcn_cvt_pkrtz(a, b);
  return __builtin_bit_cast(unsigned int, h);
}

// gat double-buffer chunk (static-named A/B ping-pong; rule #20: no runtime idx)
struct Chunk {
  short8 b0, b1, b2, b3;   // Hf: 32 j x 64 f
  uint4 e1, e2;            // E1/E2 planes, 8 f16 each per lane
  uint4 m0, m1;            // expanded 16-bit adjacency masks, rows 0/1
};

// ---- Kernel 1 (r17: W-prep ONLY, 16 blocks — X conversion folded into gemm;
// the 16 MiB Xf write + read round-trip is gone)
__global__ __launch_bounds__(256) void prep_wx(const float* __restrict__ Wsrc,
                                               unsigned short* __restrict__ Wf_hi,
                                               unsigned short* __restrict__ Wf_lo,
                                               unsigned int* __restrict__ DmaxEnc) {
  const int blk = blockIdx.x;
  const int t = threadIdx.x;
  __shared__ float lds[64][65];
  if (blk == 0 && t < 16) DmaxEnc[t] = 0u;
  const int k0 = (blk >> 2) * 64;
  const int h  = blk & 3;
  const int n0 = h * 64;
  const int c4 = (t & 15) * 4;
  #pragma unroll
  for (int rep = 0; rep < 4; ++rep) {
    const int kl = (t >> 4) + 16 * rep;
    const float4 v = *(const float4*)(Wsrc + (size_t)(k0 + kl) * HF + n0 + c4);
    lds[kl][c4 + 0] = v.x; lds[kl][c4 + 1] = v.y;
    lds[kl][c4 + 2] = v.z; lds[kl][c4 + 3] = v.w;
  }
  __syncthreads();
  #pragma unroll
  for (int rep = 0; rep < 2; ++rep) {
    const int s   = t + rep * 256;
    const int kcl = s >> 8;
    const int tt  = (s >> 6) & 3;
    const int ln  = s & 63;
    const int fL  = tt * 16 + (ln & 15);
    const int kb  = kcl * 32 + (ln >> 4) * 8;
    unsigned int hv[4], lv[4];
    #pragma unroll
    for (int p = 0; p < 4; ++p)
      split_pair(lds[kb + 2 * p][fL], lds[kb + 2 * p + 1][fL], hv[p], lv[p]);
    const size_t off = ((((size_t)h * 8 + (k0 >> 5) + kcl) * 4 + tt) << 9) + ln * 8;
    *(uint4*)(Wf_hi + off) = make_uint4(hv[0], hv[1], hv[2], hv[3]);
    *(uint4*)(Wf_lo + off) = make_uint4(lv[0], lv[1], lv[2], lv[3]);
  }
}

// ---- Kernel 2: [0..511] fused h=x@W (bf16x2 MFMA) + epilogue
//      [512..2559] adj rows -> EXPANDED 16-bit masks (0xFFFF/0x0000 per edge)
// r17: A-operand comes STRAIGHT from X (f32): each lane's fragment for kc is
// 8 consecutive floats of one row -> 2 dwordx4 + 4 split_pair, bit-identical
// to the old Xf path. All 16 loads issued up front (latency hidden by MFMA).
__global__ __launch_bounds__(256) void gemm_fused(const float* __restrict__ X,
                                                  const unsigned short* __restrict__ Wf_hi,
                                                  const unsigned short* __restrict__ Wf_lo,
                                                  const float* __restrict__ adj,
                                                  const float* __restrict__ a_src,
                                                  const float* __restrict__ a_dst,
                                                  float* __restrict__ Srcv,
                                                  unsigned short* __restrict__ E1h,
                                                  unsigned short* __restrict__ E2h,
                                                  unsigned int* __restrict__ DmaxEnc,
                                                  unsigned short* __restrict__ msk,
                                                  unsigned short* __restrict__ Hf) {
  if (blockIdx.x >= 512) {
    const int row = blockIdx.x - 512;
    const int t = threadIdx.x;                 // 0..255, 8 cols each
    const float* ar = adj + (size_t)row * N + t * 8;
    const float4 v0 = *(const float4*)(ar);
    const float4 v1 = *(const float4*)(ar + 4);
    const unsigned int d0 = (v0.x != 0.f ? 0x0000FFFFu : 0u) | (v0.y != 0.f ? 0xFFFF0000u : 0u);
    const unsigned int d1 = (v0.z != 0.f ? 0x0000FFFFu : 0u) | (v0.w != 0.f ? 0xFFFF0000u : 0u);
    const unsigned int d2 = (v1.x != 0.f ? 0x0000FFFFu : 0u) | (v1.y != 0.f ? 0xFFFF0000u : 0u);
    const unsigned int d3 = (v1.z != 0.f ? 0x0000FFFFu : 0u) | (v1.w != 0.f ? 0xFFFF0000u : 0u);
    *(uint4*)(msk + (size_t)row * N + t * 8) = make_uint4(d0, d1, d2, d3);
    return;
  }
  __shared__ unsigned short sh[64][72];
  __shared__ float smax[4];
  const int xcd  = blockIdx.x & 7;
  const int slot = blockIdx.x >> 3;
  const int mb = xcd * 16 + (slot >> 2);
  const int h  = slot & 3;
  const int w = threadIdx.x >> 6, lane = threadIdx.x & 63;
  const int fl = lane & 15, quad = lane >> 4;
  const float L2E = 1.4426950408889634f;

  const float4v zero = {0.f, 0.f, 0.f, 0.f};
  float4v acc[4] = {zero, zero, zero, zero};

  // ---- A-operand: direct f32 gather (row = own fragment row, 8 consecutive k)
  const int arow = mb * 64 + w * 16 + fl;
  const int kq   = quad * 8;
  const float* xrow = X + (size_t)arow * FIN + kq;
  float4 xa[8], xb[8];
  #pragma unroll
  for (int kc = 0; kc < 8; ++kc) {
    xa[kc] = *(const float4*)(xrow + kc * 32);
    xb[kc] = *(const float4*)(xrow + kc * 32 + 4);
  }

  #pragma unroll
  for (int kc = 0; kc < 8; ++kc) {
    unsigned int hv[4], lv[4];
    split_pair(xa[kc].x, xa[kc].y, hv[0], lv[0]);
    split_pair(xa[kc].z, xa[kc].w, hv[1], lv[1]);
    split_pair(xb[kc].x, xb[kc].y, hv[2], lv[2]);
    split_pair(xb[kc].z, xb[kc].w, hv[3], lv[3]);
    const short8 Ahi = __builtin_bit_cast(short8,
        (int4v){(int)hv[0], (int)hv[1], (int)hv[2], (int)hv[3]});
    const short8 Alo = __builtin_bit_cast(short8,
        (int4v){(int)lv[0], (int)lv[1], (int)lv[2], (int)lv[3]});
    #pragma unroll
    for (int t = 0; t < 4; ++t) {
      const size_t woff = ((((size_t)h * 8 + kc) * 4 + t) << 9) + lane * 8;
      const short8 Bhi = *(const short8*)(Wf_hi + woff);
      const short8 Blo = *(const short8*)(Wf_lo + woff);
      acc[t] = __builtin_amdgcn_mfma_f32_16x16x32_bf16(Ahi, Bhi, acc[t], 0, 0, 0);
      acc[t] = __builtin_amdgcn_mfma_f32_16x16x32_bf16(Alo, Bhi, acc[t], 0, 0, 0);
      acc[t] = __builtin_amdgcn_mfma_f32_16x16x32_bf16(Ahi, Blo, acc[t], 0, 0, 0);
    }
  }

  // ---- Src dot, E-planes (f16), wave max of d ----
  const int bb  = (mb * 64) >> 11;
  const int n0w = (mb * 64) & (N - 1);
  const int bh  = bb * H + h;
  float as[4], ad[4];
  #pragma unroll
  for (int t = 0; t < 4; ++t) {
    as[t] = a_src[h * FO + t * 16 + fl];
    ad[t] = a_dst[h * FO + t * 16 + fl];
  }
  float wmax = -INFINITY;
  #pragma unroll
  for (int reg = 0; reg < 4; ++reg) {
    float sv = 0.f, dv = 0.f;
    #pragma unroll
    for (int t = 0; t < 4; ++t) {
      sv = fmaf(acc[t][reg], as[t], sv);
      dv = fmaf(acc[t][reg], ad[t], dv);
    }
    #pragma unroll
    for (int off = 1; off <= 8; off <<= 1) {
      sv += __shfl_xor(sv, off, 64);
      dv += __shfl_xor(dv, off, 64);
    }
    wmax = fmaxf(wmax, dv);
    if (fl == 0) {
      const int node = n0w + w * 16 + quad * 4 + reg;
      Srcv[(bh << 11) + node] = sv;
      const unsigned int eu = f16pk(EXP2(dv * L2E),            // exp(d)
                                    EXP2(dv * (0.2f * L2E)));  // exp(0.2 d)
      E1h[(bh << 11) + node] = (unsigned short)(eu & 0xffffu);
      E2h[(bh << 11) + node] = (unsigned short)(eu >> 16);
    }
  }
  wmax = fmaxf(wmax, __shfl_xor(wmax, 16, 64));
  wmax = fmaxf(wmax, __shfl_xor(wmax, 32, 64));
  if (lane == 0) smax[w] = wmax;

  // ---- stage f16 tile: sh[f][node] ----
  #pragma unroll
  for (int t = 0; t < 4; ++t) {
    const int nl = w * 16 + quad * 4;
    *(unsigned int*)&sh[t * 16 + fl][nl]     = f16pk(acc[t][0], acc[t][1]);
    *(unsigned int*)&sh[t * 16 + fl][nl + 2] = f16pk(acc[t][2], acc[t][3]);
  }
  __syncthreads();
  if (threadIdx.x == 0) {
    const float bmax = fmaxf(fmaxf(smax[0], smax[1]), fmaxf(smax[2], smax[3]));
    atomicMax(DmaxEnc + bh, fenc(bmax));
  }
  // ---- fragment-ordered Hf write ----
  const int jc0 = n0w >> 5;
  #pragma unroll
  for (int rep = 0; rep < 2; ++rep) {
    const int s = (int)threadIdx.x + rep * 256;
    const int jcl = s >> 8;
    const int tt  = (s >> 6) & 3;
    const int ln  = s & 63;
    const int f    = tt * 16 + (ln & 15);
    const int node = jcl * 32 + (ln >> 4) * 8;
    unsigned short* dsth = Hf + (((size_t)bh * 64 + jc0 + jcl) * 4 + tt) * 512 + ln * 8;
    *(uint4*)dsth = *(const uint4*)&sh[f][node];
  }
}

// ---- Kernel 3: MFMA flash aggregation (r16 structure, unchanged in r17)
// Grid: B*(N/32)=256 blocks, 512 thr (8 waves: 4 heads x 2 j-halves).
// Adjacency via pre-expanded 16-bit masks (1 prefetched uint4 + 4 ANDs per row
// per it); explicit 2-deep ping-pong with static-named Chunk A/B + peeled tail.
// NOTE: plain __launch_bounds__ — min-waves bound splits unified VGPR/AGPR
// file and spills (r9: 172MB scratch traffic). Never force it.
__global__ __launch_bounds__(512) void gat_mfma(const unsigned short* __restrict__ msk,
                                                const float* __restrict__ Src,
                                                const unsigned short* __restrict__ E1h,
                                                const unsigned short* __restrict__ E2h,
                                                const unsigned int* __restrict__ DmaxEnc,
                                                const unsigned short* __restrict__ Hf,
                                                float* __restrict__ out) {
  const int xcd  = blockIdx.x & 7;
  const int slot = blockIdx.x >> 3;          // 0..31
  const int b    = xcd >> 1;
  const int i0   = ((xcd & 1) * 32 + slot) * 32;
  const int w    = threadIdx.x >> 6;         // 0..7
  const int lane = threadIdx.x & 63;
  const int h    = w & 3;
  const int jh   = w >> 2;                   // j half
  const int bh   = b * H + h;
  const int fl   = lane & 15;
  const int kk   = (lane >> 4) * 8;
  const float L2E = 1.4426950408889634f;

  const int row0 = i0 + fl;
  const int row1 = i0 + 16 + fl;
  const float dmx = fdec(DmaxEnc[bh]);
  const float s0 = Src[(bh << 11) + row0];
  const float s1 = Src[(bh << 11) + row1];
  const float u0 = s0 + dmx, m0 = fmaxf(u0, 0.2f * u0);
  const float u1 = s1 + dmx, m1 = fmaxf(u1, 0.2f * u1);
  const float c1a = EXP2((s0 - m0) * L2E), c2a = EXP2((0.2f * s0 - m0) * L2E);
  const float c1b = EXP2((s1 - m1) * L2E), c2b = EXP2((0.2f * s1 - m1) * L2E);
  // f16 row constants (all <= ~e^3.5, far inside f16 range)
  const half2v c1a2 = {(_Float16)c1a, (_Float16)c1a};
  const half2v c2a2 = {(_Float16)c2a, (_Float16)c2a};
  const half2v c1b2 = {(_Float16)c1b, (_Float16)c1b};
  const half2v c2b2 = {(_Float16)c2b, (_Float16)c2b};
  const unsigned short* mr0 = msk + (size_t)row0 * N + kk;
  const unsigned short* mr1 = msk + (size_t)row1 * N + kk;
  const unsigned short* hfb = Hf + (size_t)bh * 64 * 2048 + lane * 8;
  const unsigned short* e1b = E1h + (bh << 11);
  const unsigned short* e2b = E2h + (bh << 11);

  half8 ones;
  #pragma unroll
  for (int jj = 0; jj < 8; ++jj) ones[jj] = (_Float16)1.0f;

  const float4v zero = {0.f, 0.f, 0.f, 0.f};
  float4v acc[2][4];
  float4v accL[2];
  #pragma unroll
  for (int rt = 0; rt < 2; ++rt) {
    accL[rt] = zero;
    #pragma unroll
    for (int t = 0; t < 4; ++t) acc[rt][t] = zero;
  }

  const int jbeg = jh * (N / 2);

  auto loadc = [&](int J) -> Chunk {
    Chunk c;
    const unsigned short* hc = hfb + (size_t)(J >> 5) * 2048;
    c.b0 = *(const short8*)(hc + 0 * 512);
    c.b1 = *(const short8*)(hc + 1 * 512);
    c.b2 = *(const short8*)(hc + 2 * 512);
    c.b3 = *(const short8*)(hc + 3 * 512);
    c.e1 = *(const uint4*)(e1b + J + kk);
    c.e2 = *(const uint4*)(e2b + J + kk);
    c.m0 = *(const uint4*)(mr0 + J);
    c.m1 = *(const uint4*)(mr1 + J);
    return c;
  };

  auto compute = [&](const Chunk& c) {
    const unsigned int e1w[4] = {c.e1.x, c.e1.y, c.e1.z, c.e1.w};
    const unsigned int e2w[4] = {c.e2.x, c.e2.y, c.e2.z, c.e2.w};
    const unsigned int m0w[4] = {c.m0.x, c.m0.y, c.m0.z, c.m0.w};
    const unsigned int m1w[4] = {c.m1.x, c.m1.y, c.m1.z, c.m1.w};
    int p0i[4], p1i[4];
    #pragma unroll
    for (int p = 0; p < 4; ++p) {
      const half2v e1 = __builtin_bit_cast(half2v, e1w[p]);
      const half2v e2 = __builtin_bit_cast(half2v, e2w[p]);
      const half2v wa = __builtin_elementwise_max(c1a2 * e1, c2a2 * e2);
      const half2v wb = __builtin_elementwise_max(c1b2 * e1, c2b2 * e2);
      p0i[p] = (int)(__builtin_bit_cast(unsigned int, wa) & m0w[p]);
      p1i[p] = (int)(__builtin_bit_cast(unsigned int, wb) & m1w[p]);
    }
    const half8 p0 = __builtin_bit_cast(half8, (int4v){p0i[0], p0i[1], p0i[2], p0i[3]});
    const half8 p1 = __builtin_bit_cast(half8, (int4v){p1i[0], p1i[1], p1i[2], p1i[3]});
    const half8 hb0 = __builtin_bit_cast(half8, c.b0);
    const half8 hb1 = __builtin_bit_cast(half8, c.b1);
    const half8 hb2 = __builtin_bit_cast(half8, c.b2);
    const half8 hb3 = __builtin_bit_cast(half8, c.b3);
    acc[0][0] = __builtin_amdgcn_mfma_f32_16x16x32_f16(p0, hb0, acc[0][0], 0, 0, 0);
    acc[0][1] = __builtin_amdgcn_mfma_f32_16x16x32_f16(p0, hb1, acc[0][1], 0, 0, 0);
    acc[0][2] = __builtin_amdgcn_mfma_f32_16x16x32_f16(p0, hb2, acc[0][2], 0, 0, 0);
    acc[0][3] = __builtin_amdgcn_mfma_f32_16x16x32_f16(p0, hb3, acc[0][3], 0, 0, 0);
    accL[0]   = __builtin_amdgcn_mfma_f32_16x16x32_f16(p0, ones, accL[0], 0, 0, 0);
    acc[1][0] = __builtin_amdgcn_mfma_f32_16x16x32_f16(p1, hb0, acc[1][0], 0, 0, 0);
    acc[1][1] = __builtin_amdgcn_mfma_f32_16x16x32_f16(p1, hb1, acc[1][1], 0, 0, 0);
    acc[1][2] = __builtin_amdgcn_mfma_f32_16x16x32_f16(p1, hb2, acc[1][2], 0, 0, 0);
    acc[1][3] = __builtin_amdgcn_mfma_f32_16x16x32_f16(p1, hb3, acc[1][3], 0, 0, 0);
    accL[1]   = __builtin_amdgcn_mfma_f32_16x16x32_f16(p1, ones, accL[1], 0, 0, 0);
  };

  // ---- 2-deep ping-pong, last iteration pair peeled ----
  Chunk A = loadc(jbeg);
  for (int it = 0; it < 30; it += 2) {
    Chunk Bc = loadc(jbeg + (it + 1) * 32);
    compute(A);
    A = loadc(jbeg + (it + 2) * 32);
    compute(Bc);
  }
  {
    Chunk Bc = loadc(jbeg + 31 * 32);
    compute(A);
    compute(Bc);
  }

  // ---- combine the 2 j-halves: jh1 -> jh0 ----
  __shared__ float4v parts[4][64][11];   // 44 KiB
  if (jh == 1) {
    #pragma unroll
    for (int rt = 0; rt < 2; ++rt) {
      #pragma unroll
      for (int t = 0; t < 4; ++t) parts[h][lane][rt * 5 + t] = acc[rt][t];
      parts[h][lane][rt * 5 + 4] = accL[rt];
    }
  }
  __syncthreads();
  if (jh == 0) {
    #pragma unroll
    for (int rt = 0; rt < 2; ++rt) {
      #pragma unroll
      for (int t = 0; t < 4; ++t) acc[rt][t] += parts[h][lane][rt * 5 + t];
      accL[rt] += parts[h][lane][rt * 5 + 4];
    }
    const int quad = lane >> 4;
    #pragma unroll
    for (int rt = 0; rt < 2; ++rt) {
      #pragma unroll
      for (int reg = 0; reg < 4; ++reg) {
        const int r = i0 + rt * 16 + quad * 4 + reg;
        const float invl = 1.f / accL[rt][reg];
        float* op = out + ((size_t)(b * N) + r) * HF + h * FO + fl;
        #pragma unroll
        for (int t = 0; t < 4; ++t) op[t * 16] = acc[rt][t][reg] * invl;
      }
    }
  }
}

extern "C" void kernel_launch(void* const* d_in, const int* in_sizes, int n_in,
                              void* d_out, int out_size, void* d_ws, size_t ws_size,
                              hipStream_t stream) {
  const float* x     = (const float*)d_in[0];
  const float* adj   = (const float*)d_in[1];
  const float* W     = (const float*)d_in[2];
  const float* a_src = (const float*)d_in[3];
  const float* a_dst = (const float*)d_in[4];
  float* out = (float*)d_out;

  char* p = (char*)d_ws;
  float* Srcv = (float*)p;                  p += (size_t)B * H * N * 4;   // 128 KiB
  unsigned short* E1h = (unsigned short*)p; p += (size_t)B * H * N * 2;   // 64 KiB
  unsigned short* E2h = (unsigned short*)p; p += (size_t)B * H * N * 2;   // 64 KiB
  unsigned int* DmaxEnc = (unsigned int*)p; p += 256;
  unsigned short* Wfh = (unsigned short*)p; p += (size_t)HF * FIN * 2;    // 128 KiB
  unsigned short* Wfl = (unsigned short*)p; p += (size_t)HF * FIN * 2;    // 128 KiB
  unsigned short* Hf  = (unsigned short*)p; p += (size_t)M * HF * 2;      // 4 MiB
  unsigned short* msk = (unsigned short*)p;                               // 8 MiB

  prep_wx<<<dim3(16), dim3(256), 0, stream>>>(W, Wfh, Wfl, DmaxEnc);
  gemm_fused<<<dim3(512 + N), dim3(256), 0, stream>>>(x, Wfh, Wfl, adj,
                                                      a_src, a_dst,
                                                      Srcv, E1h, E2h, DmaxEnc,
                                                      msk, Hf);
  gat_mfma<<<dim3(B * (N / 32)), dim3(512), 0, stream>>>(msk,
                                                         Srcv, E1h, E2h, DmaxEnc, Hf, out);
}

// Round 4
// 122.391 us; speedup vs baseline: 1.0176x; 1.0176x over previous
//
#include <hip/hip_runtime.h>
#include <hip/hip_bf16.h>
#include <math.h>

#define B 4
#define N 2048
#define FIN 256
#define H 4
#define FO 64
#define M (B*N)        // 8192 rows
#define HF (H*FO)      // 256 cols

typedef __attribute__((ext_vector_type(8))) short short8;    // 8x16b (4 VGPRs)
typedef __attribute__((ext_vector_type(8))) _Float16 half8;  // MFMA f16 A/B
typedef __attribute__((ext_vector_type(2))) _Float16 half2v; // v_pk_* pair
typedef __attribute__((ext_vector_type(4))) float float4v;   // MFMA C/D
typedef __attribute__((ext_vector_type(4))) int int4v;

#if __has_builtin(__builtin_amdgcn_exp2f)
#define EXP2(x) __builtin_amdgcn_exp2f(x)
#else
#define EXP2(x) exp2f(x)
#endif

// split x into hi (truncated bf16) + lo (truncated bf16 of remainder), packed pairs
static __device__ __forceinline__ void split_pair(float x0, float x1,
                                                  unsigned int& hi, unsigned int& lo) {
  unsigned int u0 = __builtin_bit_cast(unsigned int, x0);
  unsigned int u1 = __builtin_bit_cast(unsigned int, x1);
  hi = (u0 >> 16) | (u1 & 0xffff0000u);
  float h0 = __builtin_bit_cast(float, u0 & 0xffff0000u);
  float h1 = __builtin_bit_cast(float, u1 & 0xffff0000u);
  unsigned int l0 = __builtin_bit_cast(unsigned int, x0 - h0);
  unsigned int l1 = __builtin_bit_cast(unsigned int, x1 - h1);
  lo = (l0 >> 16) | (l1 & 0xffff0000u);
}

// monotone float<->uint encoding for atomicMax
static __device__ __forceinline__ unsigned int fenc(float f) {
  unsigned int b = __builtin_bit_cast(unsigned int, f);
  return (b & 0x80000000u) ? ~b : (b | 0x80000000u);
}
static __device__ __forceinline__ float fdec(unsigned int e) {
  unsigned int b = (e & 0x80000000u) ? (e & 0x7fffffffu) : ~e;
  return __builtin_bit_cast(float, b);
}

// two f32 -> packed f16 pair (v_cvt_pkrtz_f16_f32, 1 op)
static __device__ __forceinline__ unsigned int f16pk(float a, float b) {
  auto h = __builtin_amdgcn_cvt_pkrtz(a, b);
  return __builtin_bit_cast(unsigned int, h);
}

// byte-mask (0xFF/0x00) -> two 16-bit-lane dwords: 1 v_perm each
// result lo dword = (b0,b0,b1,b1), hi dword = (b2,b2,b3,b3)
static __device__ __forceinline__ unsigned int expand_lo(unsigned int w) {
  return __builtin_amdgcn_perm(0u, w, 0x01010000u);
}
static __device__ __forceinline__ unsigned int expand_hi(unsigned int w) {
  return __builtin_amdgcn_perm(0u, w, 0x03030202u);
}

// gat pipeline chunk (static-named 4-deep rotation; rule #20: no runtime idx)
struct Chunk {
  short8 b0, b1, b2, b3;   // Hf: 32 j x 64 f
  uint4 e1, e2;            // E1/E2 planes, 8 f16 each per lane
  uint2 m0, m1;            // 8-bit adjacency masks (8 bytes), rows 0/1
};

// ---- Kernel 1: [0..15] W -> Wf (fragment-ordered bf16 hi/lo pair)
//      [16..527] X -> Xf, ONE (row-tile, k-tile) per block
__global__ __launch_bounds__(256) void prep_wx(const float* __restrict__ Wsrc,
                                               const float* __restrict__ X,
                                               unsigned short* __restrict__ Wf_hi,
                                               unsigned short* __restrict__ Wf_lo,
                                               unsigned short* __restrict__ Xf_hi,
                                               unsigned short* __restrict__ Xf_lo,
                                               unsigned int* __restrict__ DmaxEnc) {
  const int blk = blockIdx.x;
  const int t = threadIdx.x;
  __shared__ float lds[64][65];
  if (blk < 16) {
    if (blk == 0 && t < 16) DmaxEnc[t] = 0u;
    const int k0 = (blk >> 2) * 64;
    const int h  = blk & 3;
    const int n0 = h * 64;
    const int c4 = (t & 15) * 4;
    #pragma unroll
    for (int rep = 0; rep < 4; ++rep) {
      const int kl = (t >> 4) + 16 * rep;
      const float4 v = *(const float4*)(Wsrc + (size_t)(k0 + kl) * HF + n0 + c4);
      lds[kl][c4 + 0] = v.x; lds[kl][c4 + 1] = v.y;
      lds[kl][c4 + 2] = v.z; lds[kl][c4 + 3] = v.w;
    }
    __syncthreads();
    #pragma unroll
    for (int rep = 0; rep < 2; ++rep) {
      const int s   = t + rep * 256;
      const int kcl = s >> 8;
      const int tt  = (s >> 6) & 3;
      const int ln  = s & 63;
      const int fL  = tt * 16 + (ln & 15);
      const int kb  = kcl * 32 + (ln >> 4) * 8;
      unsigned int hv[4], lv[4];
      #pragma unroll
      for (int p = 0; p < 4; ++p)
        split_pair(lds[kb + 2 * p][fL], lds[kb + 2 * p + 1][fL], hv[p], lv[p]);
      const size_t off = ((((size_t)h * 8 + (k0 >> 5) + kcl) * 4 + tt) << 9) + ln * 8;
      *(uint4*)(Wf_hi + off) = make_uint4(hv[0], hv[1], hv[2], hv[3]);
      *(uint4*)(Wf_lo + off) = make_uint4(lv[0], lv[1], lv[2], lv[3]);
    }
    return;
  }
  // ---- X prep: one (xblk, ktile) per block, A-fragment order ----
  const int xb2   = blk - 16;          // 0..511
  const int xblk  = xb2 >> 2;          // 0..127 (row tile of 64)
  const int ktile = xb2 & 3;           // 0..3  (k tile of 64)
  const int mrow0 = xblk * 64;
  const int k0 = ktile * 64;
  const int c4 = (t & 15) * 4;
  #pragma unroll
  for (int rep = 0; rep < 4; ++rep) {
    const int rl = (t >> 4) + 16 * rep;
    const float4 v = *(const float4*)(X + (size_t)(mrow0 + rl) * FIN + k0 + c4);
    lds[rl][c4 + 0] = v.x; lds[rl][c4 + 1] = v.y;
    lds[rl][c4 + 2] = v.z; lds[rl][c4 + 3] = v.w;
  }
  __syncthreads();
  #pragma unroll
  for (int rep = 0; rep < 2; ++rep) {
    const int s   = t + rep * 256;
    const int mt  = s >> 7;
    const int kcl = (s >> 6) & 1;
    const int ln  = s & 63;
    const int mrl = mt * 16 + (ln & 15);
    const int kb  = kcl * 32 + (ln >> 4) * 8;
    unsigned int hv[4], lv[4];
    #pragma unroll
    for (int p = 0; p < 4; ++p)
      split_pair(lds[mrl][kb + 2 * p], lds[mrl][kb + 2 * p + 1], hv[p], lv[p]);
    const size_t off = (((size_t)(xblk * 4 + mt) * 8 + (ktile * 2 + kcl)) << 9) + ln * 8;
    *(uint4*)(Xf_hi + off) = make_uint4(hv[0], hv[1], hv[2], hv[3]);
    *(uint4*)(Xf_lo + off) = make_uint4(lv[0], lv[1], lv[2], lv[3]);
  }
}

// ---- Kernel 2: [0..511] fused h=x@W (bf16x2 MFMA) + epilogue
//      [512..2559] adj rows -> 8-bit byte masks (r18: 0xFF/0x00 per edge,
//      4.2 MiB — half of r16's 16-bit; gat expands with 1 v_perm per dword)
__global__ __launch_bounds__(256) void gemm_fused(const unsigned short* __restrict__ Xf_hi,
                                                  const unsigned short* __restrict__ Xf_lo,
                                                  const unsigned short* __restrict__ Wf_hi,
                                                  const unsigned short* __restrict__ Wf_lo,
                                                  const float* __restrict__ adj,
                                                  const float* __restrict__ a_src,
                                                  const float* __restrict__ a_dst,
                                                  float* __restrict__ Srcv,
                                                  unsigned short* __restrict__ E1h,
                                                  unsigned short* __restrict__ E2h,
                                                  unsigned int* __restrict__ DmaxEnc,
                                                  unsigned char* __restrict__ msk,
                                                  unsigned short* __restrict__ Hf) {
  if (blockIdx.x >= 512) {
    const int row = blockIdx.x - 512;
    const int t = threadIdx.x;                 // 0..255, 8 cols each
    const float* ar = adj + (size_t)row * N + t * 8;
    const float4 v0 = *(const float4*)(ar);
    const float4 v1 = *(const float4*)(ar + 4);
    const unsigned int d0 = (v0.x != 0.f ? 0x000000FFu : 0u) | (v0.y != 0.f ? 0x0000FF00u : 0u) |
                            (v0.z != 0.f ? 0x00FF0000u : 0u) | (v0.w != 0.f ? 0xFF000000u : 0u);
    const unsigned int d1 = (v1.x != 0.f ? 0x000000FFu : 0u) | (v1.y != 0.f ? 0x0000FF00u : 0u) |
                            (v1.z != 0.f ? 0x00FF0000u : 0u) | (v1.w != 0.f ? 0xFF000000u : 0u);
    *(uint2*)(msk + (size_t)row * N + t * 8) = make_uint2(d0, d1);
    return;
  }
  __shared__ unsigned short sh[64][72];
  __shared__ float smax[4];
  const int xcd  = blockIdx.x & 7;
  const int slot = blockIdx.x >> 3;
  const int mb = xcd * 16 + (slot >> 2);
  const int h  = slot & 3;
  const int w = threadIdx.x >> 6, lane = threadIdx.x & 63;
  const int fl = lane & 15, quad = lane >> 4;
  const float L2E = 1.4426950408889634f;

  const float4v zero = {0.f, 0.f, 0.f, 0.f};
  float4v acc[4] = {zero, zero, zero, zero};

  const size_t abase = (((size_t)(mb * 4 + w) * 8) << 9) + lane * 8;
  #pragma unroll
  for (int kc = 0; kc < 8; ++kc) {
    const short8 Ahi = *(const short8*)(Xf_hi + abase + ((size_t)kc << 9));
    const short8 Alo = *(const short8*)(Xf_lo + abase + ((size_t)kc << 9));
    #pragma unroll
    for (int t = 0; t < 4; ++t) {
      const size_t woff = ((((size_t)h * 8 + kc) * 4 + t) << 9) + lane * 8;
      const short8 Bhi = *(const short8*)(Wf_hi + woff);
      const short8 Blo = *(const short8*)(Wf_lo + woff);
      acc[t] = __builtin_amdgcn_mfma_f32_16x16x32_bf16(Ahi, Bhi, acc[t], 0, 0, 0);
      acc[t] = __builtin_amdgcn_mfma_f32_16x16x32_bf16(Alo, Bhi, acc[t], 0, 0, 0);
      acc[t] = __builtin_amdgcn_mfma_f32_16x16x32_bf16(Ahi, Blo, acc[t], 0, 0, 0);
    }
  }

  // ---- Src dot, E-planes (f16), wave max of d ----
  const int bb  = (mb * 64) >> 11;
  const int n0w = (mb * 64) & (N - 1);
  const int bh  = bb * H + h;
  float as[4], ad[4];
  #pragma unroll
  for (int t = 0; t < 4; ++t) {
    as[t] = a_src[h * FO + t * 16 + fl];
    ad[t] = a_dst[h * FO + t * 16 + fl];
  }
  float wmax = -INFINITY;
  #pragma unroll
  for (int reg = 0; reg < 4; ++reg) {
    float sv = 0.f, dv = 0.f;
    #pragma unroll
    for (int t = 0; t < 4; ++t) {
      sv = fmaf(acc[t][reg], as[t], sv);
      dv = fmaf(acc[t][reg], ad[t], dv);
    }
    #pragma unroll
    for (int off = 1; off <= 8; off <<= 1) {
      sv += __shfl_xor(sv, off, 64);
      dv += __shfl_xor(dv, off, 64);
    }
    wmax = fmaxf(wmax, dv);
    if (fl == 0) {
      const int node = n0w + w * 16 + quad * 4 + reg;
      Srcv[(bh << 11) + node] = sv;
      const unsigned int eu = f16pk(EXP2(dv * L2E),            // exp(d)
                                    EXP2(dv * (0.2f * L2E)));  // exp(0.2 d)
      E1h[(bh << 11) + node] = (unsigned short)(eu & 0xffffu);
      E2h[(bh << 11) + node] = (unsigned short)(eu >> 16);
    }
  }
  wmax = fmaxf(wmax, __shfl_xor(wmax, 16, 64));
  wmax = fmaxf(wmax, __shfl_xor(wmax, 32, 64));
  if (lane == 0) smax[w] = wmax;

  // ---- stage f16 tile: sh[f][node] ----
  #pragma unroll
  for (int t = 0; t < 4; ++t) {
    const int nl = w * 16 + quad * 4;
    *(unsigned int*)&sh[t * 16 + fl][nl]     = f16pk(acc[t][0], acc[t][1]);
    *(unsigned int*)&sh[t * 16 + fl][nl + 2] = f16pk(acc[t][2], acc[t][3]);
  }
  __syncthreads();
  if (threadIdx.x == 0) {
    const float bmax = fmaxf(fmaxf(smax[0], smax[1]), fmaxf(smax[2], smax[3]));
    atomicMax(DmaxEnc + bh, fenc(bmax));
  }
  // ---- fragment-ordered Hf write ----
  const int jc0 = n0w >> 5;
  #pragma unroll
  for (int rep = 0; rep < 2; ++rep) {
    const int s = (int)threadIdx.x + rep * 256;
    const int jcl = s >> 8;
    const int tt  = (s >> 6) & 3;
    const int ln  = s & 63;
    const int f    = tt * 16 + (ln & 15);
    const int node = jcl * 32 + (ln >> 4) * 8;
    unsigned short* dsth = Hf + (((size_t)bh * 64 + jc0 + jcl) * 4 + tt) * 512 + ln * 8;
    *(uint4*)dsth = *(const uint4*)&sh[f][node];
  }
}

// ---- Kernel 3: MFMA flash aggregation (r18)
// Grid: B*(N/32)=256 blocks, 512 thr (8 waves: 4 heads x 2 j-halves).
// r18: 4-deep static ping-pong (A/B/C/D) — prefetch distance 3 computes
// (~360 cyc) x 2 waves/SIMD to cover the ~900-cyc cold-HBM latency (workspace
// is re-poisoned every iteration, nothing is cache-warm). 8-bit masks expanded
// with 1 v_perm per dword (4/row/it). ~42 VALU + 10 MFMA per it.
// NOTE: plain __launch_bounds__ — min-waves bound splits unified VGPR/AGPR
// file and spills (r9: 172MB scratch traffic). Never force it.
__global__ __launch_bounds__(512) void gat_mfma(const unsigned char* __restrict__ msk,
                                                const float* __restrict__ Src,
                                                const unsigned short* __restrict__ E1h,
                                                const unsigned short* __restrict__ E2h,
                                                const unsigned int* __restrict__ DmaxEnc,
                                                const unsigned short* __restrict__ Hf,
                                                float* __restrict__ out) {
  const int xcd  = blockIdx.x & 7;
  const int slot = blockIdx.x >> 3;          // 0..31
  const int b    = xcd >> 1;
  const int i0   = ((xcd & 1) * 32 + slot) * 32;
  const int w    = threadIdx.x >> 6;         // 0..7
  const int lane = threadIdx.x & 63;
  const int h    = w & 3;
  const int jh   = w >> 2;                   // j half
  const int bh   = b * H + h;
  const int fl   = lane & 15;
  const int kk   = (lane >> 4) * 8;
  const float L2E = 1.4426950408889634f;

  const int row0 = i0 + fl;
  const int row1 = i0 + 16 + fl;
  const float dmx = fdec(DmaxEnc[bh]);
  const float s0 = Src[(bh << 11) + row0];
  const float s1 = Src[(bh << 11) + row1];
  const float u0 = s0 + dmx, m0 = fmaxf(u0, 0.2f * u0);
  const float u1 = s1 + dmx, m1 = fmaxf(u1, 0.2f * u1);
  const float c1a = EXP2((s0 - m0) * L2E), c2a = EXP2((0.2f * s0 - m0) * L2E);
  const float c1b = EXP2((s1 - m1) * L2E), c2b = EXP2((0.2f * s1 - m1) * L2E);
  // f16 row constants (all <= ~e^3.5, far inside f16 range)
  const half2v c1a2 = {(_Float16)c1a, (_Float16)c1a};
  const half2v c2a2 = {(_Float16)c2a, (_Float16)c2a};
  const half2v c1b2 = {(_Float16)c1b, (_Float16)c1b};
  const half2v c2b2 = {(_Float16)c2b, (_Float16)c2b};
  const unsigned char* mr0 = msk + (size_t)row0 * N + kk;
  const unsigned char* mr1 = msk + (size_t)row1 * N + kk;
  const unsigned short* hfb = Hf + (size_t)bh * 64 * 2048 + lane * 8;
  const unsigned short* e1b = E1h + (bh << 11);
  const unsigned short* e2b = E2h + (bh << 11);

  half8 ones;
  #pragma unroll
  for (int jj = 0; jj < 8; ++jj) ones[jj] = (_Float16)1.0f;

  const float4v zero = {0.f, 0.f, 0.f, 0.f};
  float4v acc[2][4];
  float4v accL[2];
  #pragma unroll
  for (int rt = 0; rt < 2; ++rt) {
    accL[rt] = zero;
    #pragma unroll
    for (int t = 0; t < 4; ++t) acc[rt][t] = zero;
  }

  const int jbeg = jh * (N / 2);

  auto loadc = [&](int J) -> Chunk {
    Chunk c;
    const unsigned short* hc = hfb + (size_t)(J >> 5) * 2048;
    c.b0 = *(const short8*)(hc + 0 * 512);
    c.b1 = *(const short8*)(hc + 1 * 512);
    c.b2 = *(const short8*)(hc + 2 * 512);
    c.b3 = *(const short8*)(hc + 3 * 512);
    c.e1 = *(const uint4*)(e1b + J + kk);
    c.e2 = *(const uint4*)(e2b + J + kk);
    c.m0 = *(const uint2*)(mr0 + J);
    c.m1 = *(const uint2*)(mr1 + J);
    return c;
  };

  auto compute = [&](const Chunk& c) {
    const unsigned int e1w[4] = {c.e1.x, c.e1.y, c.e1.z, c.e1.w};
    const unsigned int e2w[4] = {c.e2.x, c.e2.y, c.e2.z, c.e2.w};
    const unsigned int m0w[4] = {expand_lo(c.m0.x), expand_hi(c.m0.x),
                                 expand_lo(c.m0.y), expand_hi(c.m0.y)};
    const unsigned int m1w[4] = {expand_lo(c.m1.x), expand_hi(c.m1.x),
                                 expand_lo(c.m1.y), expand_hi(c.m1.y)};
    int p0i[4], p1i[4];
    #pragma unroll
    for (int p = 0; p < 4; ++p) {
      const half2v e1 = __builtin_bit_cast(half2v, e1w[p]);
      const half2v e2 = __builtin_bit_cast(half2v, e2w[p]);
      const half2v wa = __builtin_elementwise_max(c1a2 * e1, c2a2 * e2);
      const half2v wb = __builtin_elementwise_max(c1b2 * e1, c2b2 * e2);
      p0i[p] = (int)(__builtin_bit_cast(unsigned int, wa) & m0w[p]);
      p1i[p] = (int)(__builtin_bit_cast(unsigned int, wb) & m1w[p]);
    }
    const half8 p0 = __builtin_bit_cast(half8, (int4v){p0i[0], p0i[1], p0i[2], p0i[3]});
    const half8 p1 = __builtin_bit_cast(half8, (int4v){p1i[0], p1i[1], p1i[2], p1i[3]});
    const half8 hb0 = __builtin_bit_cast(half8, c.b0);
    const half8 hb1 = __builtin_bit_cast(half8, c.b1);
    const half8 hb2 = __builtin_bit_cast(half8, c.b2);
    const half8 hb3 = __builtin_bit_cast(half8, c.b3);
    acc[0][0] = __builtin_amdgcn_mfma_f32_16x16x32_f16(p0, hb0, acc[0][0], 0, 0, 0);
    acc[0][1] = __builtin_amdgcn_mfma_f32_16x16x32_f16(p0, hb1, acc[0][1], 0, 0, 0);
    acc[0][2] = __builtin_amdgcn_mfma_f32_16x16x32_f16(p0, hb2, acc[0][2], 0, 0, 0);
    acc[0][3] = __builtin_amdgcn_mfma_f32_16x16x32_f16(p0, hb3, acc[0][3], 0, 0, 0);
    accL[0]   = __builtin_amdgcn_mfma_f32_16x16x32_f16(p0, ones, accL[0], 0, 0, 0);
    acc[1][0] = __builtin_amdgcn_mfma_f32_16x16x32_f16(p1, hb0, acc[1][0], 0, 0, 0);
    acc[1][1] = __builtin_amdgcn_mfma_f32_16x16x32_f16(p1, hb1, acc[1][1], 0, 0, 0);
    acc[1][2] = __builtin_amdgcn_mfma_f32_16x16x32_f16(p1, hb2, acc[1][2], 0, 0, 0);
    acc[1][3] = __builtin_amdgcn_mfma_f32_16x16x32_f16(p1, hb3, acc[1][3], 0, 0, 0);
    accL[1]   = __builtin_amdgcn_mfma_f32_16x16x32_f16(p1, ones, accL[1], 0, 0, 0);
  };

  // ---- 4-deep static ping-pong (prefetch distance 3), tails peeled ----
  Chunk A  = loadc(jbeg + 0 * 32);
  Chunk Bc = loadc(jbeg + 1 * 32);
  Chunk C  = loadc(jbeg + 2 * 32);
  for (int it = 0; it < 28; it += 4) {
    Chunk D = loadc(jbeg + (it + 3) * 32);
    compute(A);
    A = loadc(jbeg + (it + 4) * 32);
    compute(Bc);
    Bc = loadc(jbeg + (it + 5) * 32);
    compute(C);
    C = loadc(jbeg + (it + 6) * 32);
    compute(D);
  }
  {
    Chunk D = loadc(jbeg + 31 * 32);
    compute(A);
    compute(Bc);
    compute(C);
    compute(D);
  }

  // ---- combine the 2 j-halves: jh1 -> jh0 ----
  __shared__ float4v parts[4][64][11];   // 44 KiB
  if (jh == 1) {
    #pragma unroll
    for (int rt = 0; rt < 2; ++rt) {
      #pragma unroll
      for (int t = 0; t < 4; ++t) parts[h][lane][rt * 5 + t] = acc[rt][t];
      parts[h][lane][rt * 5 + 4] = accL[rt];
    }
  }
  __syncthreads();
  if (jh == 0) {
    #pragma unroll
    for (int rt = 0; rt < 2; ++rt) {
      #pragma unroll
      for (int t = 0; t < 4; ++t) acc[rt][t] += parts[h][lane][rt * 5 + t];
      accL[rt] += parts[h][lane][rt * 5 + 4];
    }
    const int quad = lane >> 4;
    #pragma unroll
    for (int rt = 0; rt < 2; ++rt) {
      #pragma unroll
      for (int reg = 0; reg < 4; ++reg) {
        const int r = i0 + rt * 16 + quad * 4 + reg;
        const float invl = 1.f / accL[rt][reg];
        float* op = out + ((size_t)(b * N) + r) * HF + h * FO + fl;
        #pragma unroll
        for (int t = 0; t < 4; ++t) op[t * 16] = acc[rt][t][reg] * invl;
      }
    }
  }
}

extern "C" void kernel_launch(void* const* d_in, const int* in_sizes, int n_in,
                              void* d_out, int out_size, void* d_ws, size_t ws_size,
                              hipStream_t stream) {
  const float* x     = (const float*)d_in[0];
  const float* adj   = (const float*)d_in[1];
  const float* W     = (const float*)d_in[2];
  const float* a_src = (const float*)d_in[3];
  const float* a_dst = (const float*)d_in[4];
  float* out = (float*)d_out;

  char* p = (char*)d_ws;
  float* Srcv = (float*)p;                  p += (size_t)B * H * N * 4;   // 128 KiB
  unsigned short* E1h = (unsigned short*)p; p += (size_t)B * H * N * 2;   // 64 KiB
  unsigned short* E2h = (unsigned short*)p; p += (size_t)B * H * N * 2;   // 64 KiB
  unsigned int* DmaxEnc = (unsigned int*)p; p += 256;
  unsigned short* Wfh = (unsigned short*)p; p += (size_t)HF * FIN * 2;    // 128 KiB
  unsigned short* Wfl = (unsigned short*)p; p += (size_t)HF * FIN * 2;    // 128 KiB
  unsigned short* Xfh = (unsigned short*)p; p += (size_t)M * FIN * 2;     // 4 MiB
  unsigned short* Xfl = (unsigned short*)p; p += (size_t)M * FIN * 2;     // 4 MiB
  unsigned short* Hf  = (unsigned short*)p; p += (size_t)M * HF * 2;      // 4 MiB
  unsigned char* msk = (unsigned char*)p;                                 // 4 MiB

  prep_wx<<<dim3(528), dim3(256), 0, stream>>>(W, x, Wfh, Wfl, Xfh, Xfl, DmaxEnc);
  gemm_fused<<<dim3(512 + N), dim3(256), 0, stream>>>(Xfh, Xfl, Wfh, Wfl, adj,
                                                      a_src, a_dst,
                                                      Srcv, E1h, E2h, DmaxEnc,
                                                      msk, Hf);
  gat_mfma<<<dim3(B * (N / 32)), dim3(512), 0, stream>>>(msk,
                                                         Srcv, E1h, E2h, DmaxEnc, Hf, out);
}